// Round 2
// baseline (636.877 us; speedup 1.0000x reference)
//
#include <hip/hip_runtime.h>

#define S_   512
#define B_   64
#define H_   1024
#define E_   512
#define V_   32000
#define TWOH 2048
#define KIN  2560           // 2H + E
#define KCAT 3584           // 2H + E + H
#define G4   4096
#define NCH  32             // attention S-chunks (one wave each)
#define SPC  (S_ / NCH)     // 16 s per chunk

// ws byte layout (f32 partials)
#define P_STRIDE 8208                        // m,l fp32 + pad to 16 + 2048 f32
#define A1_OFF   16809984                    // 64*32*8208
#define GP_OFF   17268736                    // A1_OFF + 64*3584*2
#define H1_OFF   19365888                    // GP_OFF + 2*64*4096*4
// total ws use: 19,496,960 bytes (~19.5 MB)

typedef unsigned short u16;
typedef unsigned int   u32;

using f32x4 = __attribute__((ext_vector_type(4))) float;
using s16x8 = __attribute__((ext_vector_type(8))) short;

__device__ __forceinline__ u16 f2bf(float f) {
    union { float f; u32 u; } v; v.f = f;
    u32 r = v.u + 0x7fffu + ((v.u >> 16) & 1u);
    return (u16)(r >> 16);
}
__device__ __forceinline__ s16x8 pack_frag(const float* p) {
    s16x8 r;
#pragma unroll
    for (int j = 0; j < 8; j++) r[j] = (short)f2bf(p[j]);
    return r;
}

// K1: one wave per (b, s-chunk). Online-softmax partial over 16 s values.
// Lane t-element mapping: d = j*256 + lane*4 + c  (8 float4 chunks per 2048 row)
__global__ __launch_bounds__(64)
void attn_partial(const float* __restrict__ enc, const float* __restrict__ h0,
                  const float* __restrict__ Wen, const float* __restrict__ be,
                  char* __restrict__ wsP) {
    const int b = blockIdx.y, ch = blockIdx.x, lane = threadIdx.x;

    // w_e fragment (32 of 2048)
    float we[32];
#pragma unroll
    for (int j = 0; j < 8; j++)
        *(float4*)&we[j * 4] = *(const float4*)(Wen + H_ + j * 256 + lane * 4);

    // hd = h0[b] . w_h + b_energy
    float hd = 0.f;
#pragma unroll
    for (int j = 0; j < 4; j++) {
        const float4 hv = *(const float4*)(h0 + b * H_ + j * 256 + lane * 4);
        const float4 wv = *(const float4*)(Wen + j * 256 + lane * 4);
        hd += hv.x * wv.x + hv.y * wv.y + hv.z * wv.z + hv.w * wv.w;
    }
    for (int off = 32; off > 0; off >>= 1) hd += __shfl_xor(hd, off, 64);
    hd += be[0];

    float m = -1e30f, l = 0.f, ctx[32];
#pragma unroll
    for (int i = 0; i < 32; i++) ctx[i] = 0.f;

    const int s0 = ch * SPC;
    for (int si = 0; si < SPC; si++) {
        const float* eb = enc + ((size_t)(s0 + si) * B_ + b) * TWOH;
        float ev[32];
#pragma unroll
        for (int j = 0; j < 8; j++)
            *(float4*)&ev[j * 4] = *(const float4*)(eb + j * 256 + lane * 4);
        float dot = 0.f;
#pragma unroll
        for (int i = 0; i < 32; i++) dot += ev[i] * we[i];
        for (int off = 32; off > 0; off >>= 1) dot += __shfl_xor(dot, off, 64);
        const float e  = fmaxf(dot + hd, 0.f);
        const float mn = fmaxf(m, e);
        const float al = __expf(m - mn), p = __expf(e - mn);
        l = l * al + p;
#pragma unroll
        for (int i = 0; i < 32; i++) ctx[i] = ctx[i] * al + p * ev[i];
        m = mn;
    }

    char* pb = wsP + (size_t)(b * NCH + ch) * P_STRIDE;
    if (lane == 0) { ((float*)pb)[0] = m; ((float*)pb)[1] = l; }
    float* pc = (float*)(pb + 16);
#pragma unroll
    for (int j = 0; j < 8; j++)
        *(float4*)(pc + j * 256 + lane * 4) = *(const float4*)&ctx[j * 4];
}

// K2: merge 32 partials per b; build A1 = [context | emb[x[b]] | h0] bf16 (64 x 3584)
__global__ __launch_bounds__(256)
void attn_merge(const char* __restrict__ wsP, u16* __restrict__ A1,
                const int* __restrict__ x, const float* __restrict__ emb,
                const float* __restrict__ h0) {
    const int b = blockIdx.x, t = threadIdx.x;
    __shared__ float sm[NCH], sl[NCH];
    if (t < NCH) {
        const float* pf = (const float*)(wsP + (size_t)(b * NCH + t) * P_STRIDE);
        sm[t] = pf[0]; sl[t] = pf[1];
    }
    __syncthreads();
    float M = -1e30f;
    for (int i = 0; i < NCH; i++) M = fmaxf(M, sm[i]);
    float L = 0.f;
    for (int i = 0; i < NCH; i++) L += sl[i] * __expf(sm[i] - M);
    const float inv = 1.f / L;

    float acc[8];
#pragma unroll
    for (int q = 0; q < 8; q++) acc[q] = 0.f;
    const int d = t * 8;
    for (int i = 0; i < NCH; i++) {
        const float w = __expf(sm[i] - M);
        const float* pc = (const float*)(wsP + (size_t)(b * NCH + i) * P_STRIDE + 16);
        const float4 v0 = *(const float4*)(pc + d);
        const float4 v1 = *(const float4*)(pc + d + 4);
        acc[0] += w * v0.x; acc[1] += w * v0.y; acc[2] += w * v0.z; acc[3] += w * v0.w;
        acc[4] += w * v1.x; acc[5] += w * v1.y; acc[6] += w * v1.z; acc[7] += w * v1.w;
    }
#pragma unroll
    for (int q = 0; q < 8; q++) acc[q] *= inv;

    u16* row = A1 + b * KCAT;
    uint4 cw;
    cw.x = (u32)f2bf(acc[0]) | ((u32)f2bf(acc[1]) << 16);
    cw.y = (u32)f2bf(acc[2]) | ((u32)f2bf(acc[3]) << 16);
    cw.z = (u32)f2bf(acc[4]) | ((u32)f2bf(acc[5]) << 16);
    cw.w = (u32)f2bf(acc[6]) | ((u32)f2bf(acc[7]) << 16);
    *(uint4*)(row + d) = cw;
    // emb gather (512 els, 2/thread)
    const int xb = x[b];
    const float2 ev = *(const float2*)(emb + (size_t)xb * E_ + t * 2);
    *(u32*)(row + TWOH + t * 2) = (u32)f2bf(ev.x) | ((u32)f2bf(ev.y) << 16);
    // h0 copy (1024 els, 4/thread)
    const float4 hv = *(const float4*)(h0 + b * H_ + t * 4);
    uint2 hw;
    hw.x = (u32)f2bf(hv.x) | ((u32)f2bf(hv.y) << 16);
    hw.y = (u32)f2bf(hv.z) | ((u32)f2bf(hv.w) << 16);
    *(uint2*)(row + KIN + t * 4) = hw;
}

// K3: gates = A1 @ [W_ih | W_hh]^T, MFMA 16x16x32 bf16, M=64, wave tile 64x16,
// K-split x2 into separate partial buffers. W loaded f32, cast to bf16 (lossless:
// harness values are bf16-rounded).
__global__ __launch_bounds__(256)
void gemm_gates(const u16* __restrict__ A1, const float* __restrict__ Wih,
                const float* __restrict__ Whh, float* __restrict__ gp) {
    const int wave = threadIdx.x >> 6, lane = threadIdx.x & 63;
    const int quad = lane >> 4, l16 = lane & 15;
    const int n0 = blockIdx.x * 64 + wave * 16;
    const int split = blockIdx.y;
    const int kbeg = split ? 1792 : 0;
    const int kend = split ? KCAT : 1792;
    const int r = n0 + l16;

    f32x4 acc[4];
#pragma unroll
    for (int mi = 0; mi < 4; mi++) acc[mi] = (f32x4){0.f, 0.f, 0.f, 0.f};

    for (int k = kbeg; k < kend; k += 32) {
        const int kq = k + quad * 8;
        float wv[8];
        if (k < KIN) {
            *(float4*)&wv[0] = *(const float4*)(Wih + (size_t)r * KIN + kq);
            *(float4*)&wv[4] = *(const float4*)(Wih + (size_t)r * KIN + kq + 4);
        } else {
            *(float4*)&wv[0] = *(const float4*)(Whh + (size_t)r * H_ + (kq - KIN));
            *(float4*)&wv[4] = *(const float4*)(Whh + (size_t)r * H_ + (kq - KIN) + 4);
        }
        const s16x8 bfr = pack_frag(wv);
#pragma unroll
        for (int mi = 0; mi < 4; mi++) {
            const s16x8 afr = *(const s16x8*)(A1 + (size_t)(mi * 16 + l16) * KCAT + kq);
            acc[mi] = __builtin_amdgcn_mfma_f32_16x16x32_bf16(afr, bfr, acc[mi], 0, 0, 0);
        }
    }
    float* out = gp + (size_t)split * B_ * G4;
#pragma unroll
    for (int mi = 0; mi < 4; mi++)
#pragma unroll
        for (int reg = 0; reg < 4; reg++)
            out[(size_t)(mi * 16 + quad * 4 + reg) * G4 + n0 + l16] = acc[mi][reg];
}

// K4: LSTM elementwise epilogue (f32 out)
__global__ __launch_bounds__(256)
void lstm_ep(const float* __restrict__ gp, const float* __restrict__ bih,
             const float* __restrict__ bhh, const float* __restrict__ c0,
             float* __restrict__ out, u16* __restrict__ h1b) {
    const int idx = blockIdx.x * 256 + threadIdx.x;
    const int b = idx >> 10, u = idx & 1023;
    const float* g0 = gp + (size_t)b * G4;
    const float* g1 = gp + (size_t)B_ * G4 + (size_t)b * G4;
    const float gi = g0[u]        + g1[u]        + bih[u]        + bhh[u];
    const float gf = g0[u + 1024] + g1[u + 1024] + bih[u + 1024] + bhh[u + 1024];
    const float gg = g0[u + 2048] + g1[u + 2048] + bih[u + 2048] + bhh[u + 2048];
    const float go = g0[u + 3072] + g1[u + 3072] + bih[u + 3072] + bhh[u + 3072];
    const float c0v = c0[idx];
    const float si = 1.f / (1.f + __expf(-gi));
    const float sf = 1.f / (1.f + __expf(-gf));
    const float so = 1.f / (1.f + __expf(-go));
    const float c1 = sf * c0v + si * tanhf(gg);
    const float h1 = so * tanhf(c1);
    out[2048000 + idx] = h1;
    out[2113536 + idx] = c1;
    h1b[idx] = f2bf(h1);
}

// K5: pred = h1 @ W_fc^T + b_fc, MFMA, M=64, wave tile 64x16, 500 blocks
__global__ __launch_bounds__(256)
void gemm_fc(const u16* __restrict__ h1b, const float* __restrict__ Wfc,
             const float* __restrict__ bfc, float* __restrict__ pred) {
    const int wave = threadIdx.x >> 6, lane = threadIdx.x & 63;
    const int quad = lane >> 4, l16 = lane & 15;
    const int n0 = blockIdx.x * 64 + wave * 16;
    const int r = n0 + l16;

    f32x4 acc[4];
#pragma unroll
    for (int mi = 0; mi < 4; mi++) acc[mi] = (f32x4){0.f, 0.f, 0.f, 0.f};

    for (int k = 0; k < H_; k += 32) {
        const int kq = k + quad * 8;
        float wv[8];
        *(float4*)&wv[0] = *(const float4*)(Wfc + (size_t)r * H_ + kq);
        *(float4*)&wv[4] = *(const float4*)(Wfc + (size_t)r * H_ + kq + 4);
        const s16x8 bfr = pack_frag(wv);
#pragma unroll
        for (int mi = 0; mi < 4; mi++) {
            const s16x8 afr = *(const s16x8*)(h1b + (size_t)(mi * 16 + l16) * H_ + kq);
            acc[mi] = __builtin_amdgcn_mfma_f32_16x16x32_bf16(afr, bfr, acc[mi], 0, 0, 0);
        }
    }
    const float bv = bfc[r];
#pragma unroll
    for (int mi = 0; mi < 4; mi++)
#pragma unroll
        for (int reg = 0; reg < 4; reg++)
            pred[(size_t)(mi * 16 + quad * 4 + reg) * V_ + n0 + l16] = acc[mi][reg] + bv;
}

extern "C" void kernel_launch(void* const* d_in, const int* in_sizes, int n_in,
                              void* d_out, int out_size, void* d_ws, size_t ws_size,
                              hipStream_t stream) {
    const int*   x   = (const int*)d_in[0];
    const float* enc = (const float*)d_in[1];
    const float* hid = (const float*)d_in[2];
    const float* cel = (const float*)d_in[3];
    const float* emb = (const float*)d_in[4];
    const float* Wen = (const float*)d_in[5];
    const float* be  = (const float*)d_in[6];
    const float* Wih = (const float*)d_in[7];
    const float* Whh = (const float*)d_in[8];
    const float* bih = (const float*)d_in[9];
    const float* bhh = (const float*)d_in[10];
    const float* Wfc = (const float*)d_in[11];
    const float* bfc = (const float*)d_in[12];
    float* out = (float*)d_out;
    char*  ws  = (char*)d_ws;

    char*  wsP = ws;
    u16*   A1  = (u16*)(ws + A1_OFF);
    float* gp  = (float*)(ws + GP_OFF);
    u16*   h1b = (u16*)(ws + H1_OFF);

    attn_partial<<<dim3(NCH, B_), dim3(64), 0, stream>>>(enc, hid, Wen, be, wsP);
    attn_merge  <<<dim3(B_),      dim3(256), 0, stream>>>(wsP, A1, x, emb, hid);
    gemm_gates  <<<dim3(G4 / 64, 2), dim3(256), 0, stream>>>(A1, Wih, Whh, gp);
    lstm_ep     <<<dim3((B_ * H_) / 256), dim3(256), 0, stream>>>(gp, bih, bhh, cel, out, h1b);
    gemm_fc     <<<dim3(V_ / 64), dim3(256), 0, stream>>>(h1b, Wfc, bfc, out);
}